// Round 11
// baseline (452.565 us; speedup 1.0000x reference)
//
#include <hip/hip_runtime.h>
#include <math.h>

#define NN 50000
#define NE 640000
#define NR 8
#define SCAN_N (NN * NR)  // 400000 segments
#define SCAN_CH 2048      // elements per scan block
#define SCAN_NB ((SCAN_N + SCAN_CH - 1) / SCAN_CH)  // 196

typedef __attribute__((ext_vector_type(8))) _Float16 half8;
typedef __attribute__((ext_vector_type(8))) short short8;
typedef __attribute__((ext_vector_type(4))) float f32x4;
typedef __attribute__((ext_vector_type(4))) unsigned short u16x4;
typedef const void __attribute__((address_space(1))) gvoid_t;
typedef void __attribute__((address_space(3))) svoid_t;

__device__ __forceinline__ unsigned short f2h(float f) {
    _Float16 h = (_Float16)f;                       // v_cvt_f16_f32, RNE
    return __builtin_bit_cast(unsigned short, h);
}
__device__ __forceinline__ float h2f(unsigned short u) {
    return (float)__builtin_bit_cast(_Float16, u);
}

// ---------- preprocessing ----------
__global__ __launch_bounds__(256) void count_kernel(const int* __restrict__ dst,
                                                    const int* __restrict__ typ,
                                                    int* __restrict__ cnt, int E) {
    int e = blockIdx.x * 256 + threadIdx.x;
    if (e < E) atomicAdd(&cnt[dst[e] * NR + typ[e]], 1);
}

__global__ __launch_bounds__(256) void inv_kernel(const int* __restrict__ cnt,
                                                  float* __restrict__ inv, int n) {
    int i = blockIdx.x * 256 + threadIdx.x;
    if (i < n) {
        int c = cnt[i];
        inv[i] = 1.0f / (float)(c > 1 ? c : 1);
    }
}

// ---- hierarchical scan
__global__ __launch_bounds__(256) void scan1_kernel(const int* __restrict__ cnt,
                                                    int* __restrict__ loc,
                                                    int* __restrict__ bsum) {
    __shared__ int s[256];
    const int t = threadIdx.x;
    const int base = blockIdx.x * SCAN_CH + t * 8;
    int v[8];
    int sum = 0;
#pragma unroll
    for (int j = 0; j < 8; ++j) {
        int idx = base + j;
        v[j] = (idx < SCAN_N) ? cnt[idx] : 0;
        sum += v[j];
    }
    s[t] = sum;
    __syncthreads();
    for (int off = 1; off < 256; off <<= 1) {
        int u = (t >= off) ? s[t - off] : 0;
        __syncthreads();
        s[t] += u;
        __syncthreads();
    }
    int run = (t == 0) ? 0 : s[t - 1];
#pragma unroll
    for (int j = 0; j < 8; ++j) {
        int idx = base + j;
        if (idx < SCAN_N) loc[idx] = run;
        run += v[j];
    }
    if (t == 255) bsum[blockIdx.x] = s[255];
}

__global__ __launch_bounds__(256) void scan2_kernel(const int* __restrict__ bsum,
                                                    int* __restrict__ boff, int nb) {
    __shared__ int s[256];
    const int t = threadIdx.x;
    s[t] = (t < nb) ? bsum[t] : 0;
    __syncthreads();
    for (int off = 1; off < 256; off <<= 1) {
        int u = (t >= off) ? s[t - off] : 0;
        __syncthreads();
        s[t] += u;
        __syncthreads();
    }
    if (t < nb) boff[t] = (t == 0) ? 0 : s[t - 1];
    if (t == nb - 1) boff[nb] = s[t];
}

__global__ __launch_bounds__(256) void scan3_kernel(int* __restrict__ rowptr,
                                                    int* __restrict__ start,
                                                    const int* __restrict__ boff, int nb) {
    const int b = blockIdx.x, t = threadIdx.x;
    const int add = boff[b];
#pragma unroll
    for (int j = 0; j < 8; ++j) {
        int idx = b * SCAN_CH + t * 8 + j;
        if (idx < SCAN_N) {
            int v = rowptr[idx] + add;
            rowptr[idx] = v;
            start[idx] = v;
        }
    }
    if (b == 0 && t == 0) rowptr[SCAN_N] = boff[nb];
}

// counting-sort by (dst,rel): srcrel[pos] = src | rel<<20
__global__ __launch_bounds__(256) void fill_kernel(const int* __restrict__ src,
                                                   const int* __restrict__ dst,
                                                   const int* __restrict__ typ,
                                                   int* __restrict__ start,
                                                   int* __restrict__ srcrel, int E) {
    int e = blockIdx.x * 256 + threadIdx.x;
    if (e >= E) return;
    int r = typ[e];
    int pos = atomicAdd(&start[dst[e] * NR + r], 1);
    srcrel[pos] = src[e] | (r << 20);
}

// ---------- x (fp32, [NN,128]) -> xh (fp16) ----------
__global__ __launch_bounds__(256) void cvt_kernel(const float* __restrict__ x,
                                                  unsigned short* __restrict__ xh, int n4) {
    int i = blockIdx.x * 256 + threadIdx.x;
    if (i >= n4) return;
    float4 v = ((const float4*)x)[i];
    uint2 u;
    u.x = (unsigned)f2h(v.x) | ((unsigned)f2h(v.y) << 16);
    u.y = (unsigned)f2h(v.z) | ((unsigned)f2h(v.w) << 16);
    ((uint2*)xh)[i] = u;
}

// ---------- weight pack: Bt[n][k] fp16, n in [0,9*O): n<8*O -> W[r=n/O][k][o=n%O], else root[k][n-8*O]
__global__ __launch_bounds__(256) void pack_b_kernel(const float* __restrict__ W,
                                                     const float* __restrict__ root,
                                                     unsigned short* __restrict__ Bt, int O) {
    int i = blockIdx.x * 256 + threadIdx.x;
    int NTOT = 9 * O;
    if (i >= NTOT * 128) return;
    int k = i & 127, n = i >> 7;
    float v = (n < 8 * O) ? W[(size_t)(n / O) * 128 * O + (size_t)k * O + (n % O)]
                          : root[(size_t)k * O + (n - 8 * O)];
    Bt[(size_t)n * 128 + k] = f2h(v);
}

// ---------- fp16 MFMA GEMM: C[M,LDC] = A[M,128] @ Bt[LDC,128]^T, fp16 out ----------
// R6 body (fastest measured: 2-phase BK=64, 16KB LDS, 71% occ) + contiguous
// 8B epilogue via swapped mfma(bf, af) + NONTEMPORAL C stores (skip RFO).
template <int LDC>
__global__ __launch_bounds__(256) void gemm_xw(const unsigned short* __restrict__ A,
                                               const unsigned short* __restrict__ Bt,
                                               unsigned short* __restrict__ C) {
    __shared__ __align__(16) unsigned short As[64 * 64];
    __shared__ __align__(16) unsigned short Bs[64 * 64];
    const int t = threadIdx.x;
    const int w = t >> 6, lane = t & 63;
    const int q = lane >> 4, m = lane & 15;
    const int wr = w >> 1, wc = w & 1;     // 2x2 wave grid: 32x32 per wave
    const int bm = blockIdx.y * 64;
    const int bn = blockIdx.x * 64;

    f32x4 acc[2][2];
#pragma unroll
    for (int mb = 0; mb < 2; ++mb)
#pragma unroll
        for (int nb = 0; nb < 2; ++nb) acc[mb][nb] = (f32x4)0.f;

    const int srow = lane >> 3, schk = lane & 7;   // lane -> (row-in-8, 16B chunk)

#pragma unroll
    for (int kc = 0; kc < 2; ++kc) {
        const int k0 = kc * 64;
        // A tile: 64 rows x 64 fp16 (8 KB)
#pragma unroll
        for (int ii = 0; ii < 2; ++ii) {
            int i = w * 2 + ii;
            int grow = bm + i * 8 + srow;
            if (grow >= NN) grow = NN - 1;
            const unsigned short* g = A + (size_t)grow * 128 + k0 + schk * 8;
            __builtin_amdgcn_global_load_lds((gvoid_t*)g, (svoid_t*)(As + i * 512), 16, 0, 0);
        }
        // B tile: 64 rows of Bt x 64 fp16
#pragma unroll
        for (int ii = 0; ii < 2; ++ii) {
            int i = w * 2 + ii;
            const unsigned short* g = Bt + (size_t)(bn + i * 8 + srow) * 128 + k0 + schk * 8;
            __builtin_amdgcn_global_load_lds((gvoid_t*)g, (svoid_t*)(Bs + i * 512), 16, 0, 0);
        }
        __syncthreads();
#pragma unroll
        for (int s = 0; s < 2; ++s) {
            half8 af[2], bf[2];
#pragma unroll
            for (int mb = 0; mb < 2; ++mb)
                af[mb] = __builtin_bit_cast(half8,
                    *(const short8*)(As + (wr * 32 + mb * 16 + m) * 64 + s * 32 + q * 8));
#pragma unroll
            for (int nb = 0; nb < 2; ++nb)
                bf[nb] = __builtin_bit_cast(half8,
                    *(const short8*)(Bs + (wc * 32 + nb * 16 + m) * 64 + s * 32 + q * 8));
#pragma unroll
            for (int mb = 0; mb < 2; ++mb)
#pragma unroll
                for (int nb = 0; nb < 2; ++nb)
                    acc[mb][nb] = __builtin_amdgcn_mfma_f32_16x16x32_f16(bf[nb], af[mb],
                                                                         acc[mb][nb], 0, 0, 0);
        }
        __syncthreads();
    }

    // epilogue (swapped-operand layout): row = block + m, cols = q*4 + j (contiguous)
    // nontemporal: C is written once, consumed by the next kernel — don't RFO/cache.
#pragma unroll
    for (int mb = 0; mb < 2; ++mb) {
        int grow = bm + wr * 32 + mb * 16 + m;
        if (grow >= NN) continue;
#pragma unroll
        for (int nb = 0; nb < 2; ++nb) {
            int col = bn + wc * 32 + nb * 16 + q * 4;
            u16x4 u;
            u.x = f2h(acc[mb][nb][0]);
            u.y = f2h(acc[mb][nb][1]);
            u.z = f2h(acc[mb][nb][2]);
            u.w = f2h(acc[mb][nb][3]);
            __builtin_nontemporal_store(u, (u16x4*)(C + (size_t)grow * LDC + col));
        }
    }
}

// ---------- aggregation over transformed messages: one wave per dst ----------
// O=128: h[dst] = sum_e half2(XW[src_e, r_e*128 + 2*lane..]) * inv[dst,r_e]
//                 + XW[dst, 1024..] + bias  -> fp16 h1b
// O=64, FINAL: scalar per lane + sigmoid -> fp32 out
template <int O, bool FINAL>
__global__ __launch_bounds__(256) void agg_kernel(const int* __restrict__ rp,
                                                  const int* __restrict__ srcrel,
                                                  const float* __restrict__ inv,
                                                  const unsigned short* __restrict__ XW,
                                                  const float* __restrict__ bias,
                                                  void* __restrict__ Hout) {
    __shared__ float sinv[4][8];
    const int slot = threadIdx.x >> 6, lane = threadIdx.x & 63;
    const int w = blockIdx.x * 4 + slot;
    if (w >= NN) return;
    if (lane < 8) sinv[slot][lane] = inv[w * NR + lane];   // wave-synchronous, no barrier

    const int beg = rp[w * NR], end = rp[w * NR + NR];
    constexpr int LDC2 = 9 * O / 2;          // row stride in half2 units (576 or 288)

    if (O == 128) {
        const unsigned int* X2 = (const unsigned int*)XW;   // half2 units
        float2 acc = make_float2(0.f, 0.f);
        int i = beg;
        for (; i + 3 < end; i += 4) {        // 4 gathers in flight
            int p0 = srcrel[i], p1 = srcrel[i + 1], p2 = srcrel[i + 2], p3 = srcrel[i + 3];
            unsigned g0 = X2[(size_t)(p0 & 0xFFFFF) * LDC2 + (((unsigned)p0) >> 20) * 64 + lane];
            unsigned g1 = X2[(size_t)(p1 & 0xFFFFF) * LDC2 + (((unsigned)p1) >> 20) * 64 + lane];
            unsigned g2 = X2[(size_t)(p2 & 0xFFFFF) * LDC2 + (((unsigned)p2) >> 20) * 64 + lane];
            unsigned g3 = X2[(size_t)(p3 & 0xFFFFF) * LDC2 + (((unsigned)p3) >> 20) * 64 + lane];
            float s0 = sinv[slot][((unsigned)p0) >> 20];
            float s1 = sinv[slot][((unsigned)p1) >> 20];
            float s2 = sinv[slot][((unsigned)p2) >> 20];
            float s3 = sinv[slot][((unsigned)p3) >> 20];
            acc.x += h2f((unsigned short)(g0 & 0xFFFFu)) * s0;
            acc.y += h2f((unsigned short)(g0 >> 16)) * s0;
            acc.x += h2f((unsigned short)(g1 & 0xFFFFu)) * s1;
            acc.y += h2f((unsigned short)(g1 >> 16)) * s1;
            acc.x += h2f((unsigned short)(g2 & 0xFFFFu)) * s2;
            acc.y += h2f((unsigned short)(g2 >> 16)) * s2;
            acc.x += h2f((unsigned short)(g3 & 0xFFFFu)) * s3;
            acc.y += h2f((unsigned short)(g3 >> 16)) * s3;
        }
        for (; i < end; ++i) {
            int p0 = srcrel[i];
            unsigned g0 = X2[(size_t)(p0 & 0xFFFFF) * LDC2 + (((unsigned)p0) >> 20) * 64 + lane];
            float s0 = sinv[slot][((unsigned)p0) >> 20];
            acc.x += h2f((unsigned short)(g0 & 0xFFFFu)) * s0;
            acc.y += h2f((unsigned short)(g0 >> 16)) * s0;
        }
        // root block (cols 1024..1151 = half2 512..575) + bias
        unsigned rt = X2[(size_t)w * LDC2 + 512 + lane];
        float2 bv = ((const float2*)bias)[lane];
        float vx = acc.x + h2f((unsigned short)(rt & 0xFFFFu)) + bv.x;
        float vy = acc.y + h2f((unsigned short)(rt >> 16)) + bv.y;
        ((unsigned int*)Hout)[(size_t)w * 64 + lane] =
            (unsigned)f2h(vx) | ((unsigned)f2h(vy) << 16);
    } else {
        constexpr int LDC = 9 * O;           // 576
        float acc = 0.f;
        int i = beg;
        for (; i + 3 < end; i += 4) {
            int p0 = srcrel[i], p1 = srcrel[i + 1], p2 = srcrel[i + 2], p3 = srcrel[i + 3];
            unsigned short g0 = XW[(size_t)(p0 & 0xFFFFF) * LDC + (((unsigned)p0) >> 20) * 64 + lane];
            unsigned short g1 = XW[(size_t)(p1 & 0xFFFFF) * LDC + (((unsigned)p1) >> 20) * 64 + lane];
            unsigned short g2 = XW[(size_t)(p2 & 0xFFFFF) * LDC + (((unsigned)p2) >> 20) * 64 + lane];
            unsigned short g3 = XW[(size_t)(p3 & 0xFFFFF) * LDC + (((unsigned)p3) >> 20) * 64 + lane];
            acc += h2f(g0) * sinv[slot][((unsigned)p0) >> 20];
            acc += h2f(g1) * sinv[slot][((unsigned)p1) >> 20];
            acc += h2f(g2) * sinv[slot][((unsigned)p2) >> 20];
            acc += h2f(g3) * sinv[slot][((unsigned)p3) >> 20];
        }
        for (; i < end; ++i) {
            int p0 = srcrel[i];
            unsigned short g0 = XW[(size_t)(p0 & 0xFFFFF) * LDC + (((unsigned)p0) >> 20) * 64 + lane];
            acc += h2f(g0) * sinv[slot][((unsigned)p0) >> 20];
        }
        float v = acc + h2f(XW[(size_t)w * LDC + 512 + lane]) + bias[lane];
        ((float*)Hout)[(size_t)w * 64 + lane] = 1.f / (1.f + __expf(-v));
    }
}

extern "C" void kernel_launch(void* const* d_in, const int* in_sizes, int n_in,
                              void* d_out, int out_size, void* d_ws, size_t ws_size,
                              hipStream_t stream) {
    const float* x     = (const float*)d_in[0];
    const int*   esrc  = (const int*)d_in[1];
    const int*   edst  = (const int*)d_in[2];
    const int*   etyp  = (const int*)d_in[3];
    const float* W1    = (const float*)d_in[4];
    const float* root1 = (const float*)d_in[5];
    const float* b1    = (const float*)d_in[6];
    const float* W2    = (const float*)d_in[7];
    const float* root2 = (const float*)d_in[8];
    const float* b2    = (const float*)d_in[9];
    float* out = (float*)d_out;

    char* ws = (char*)d_ws;
    unsigned short* Bt1    = (unsigned short*)ws; ws += (size_t)1152 * 128 * 2; // 288 KB
    unsigned short* Bt2    = (unsigned short*)ws; ws += (size_t)576 * 128 * 2;  // 144 KB
    int*            cnt    = (int*)ws;            ws += (size_t)SCAN_N * 4;     // 1.6 MB
    float*          inv    = (float*)ws;          ws += (size_t)SCAN_N * 4;     // 1.6 MB
    int*            rp     = (int*)ws;            ws += (size_t)(SCAN_N + 64) * 4;
    int*            start  = (int*)ws;            ws += (size_t)SCAN_N * 4;     // 1.6 MB
    int*            bsum   = (int*)ws;            ws += (size_t)256 * 4;
    int*            boff   = (int*)ws;            ws += (size_t)257 * 4;
    int*            srcrel = (int*)ws;            ws += (size_t)NE * 4;         // 2.56 MB
    unsigned short* xh     = (unsigned short*)ws; ws += (size_t)NN * 128 * 2;   // 12.8 MB
    unsigned short* h1b    = (unsigned short*)ws; ws += (size_t)NN * 128 * 2;   // 12.8 MB
    unsigned short* xW     = (unsigned short*)ws;                               // 115.2 MB
    unsigned short* xW2    = xW;   // layer-2 transform aliases (xW dead after agg1)

    // CSR by (dst, rel) — hierarchical scan, fully parallel
    (void)hipMemsetAsync(cnt, 0, (size_t)SCAN_N * 4, stream);
    count_kernel<<<(NE + 255) / 256, 256, 0, stream>>>(edst, etyp, cnt, NE);
    inv_kernel<<<(SCAN_N + 255) / 256, 256, 0, stream>>>(cnt, inv, SCAN_N);
    scan1_kernel<<<SCAN_NB, 256, 0, stream>>>(cnt, rp, bsum);
    scan2_kernel<<<1, 256, 0, stream>>>(bsum, boff, SCAN_NB);
    scan3_kernel<<<SCAN_NB, 256, 0, stream>>>(rp, start, boff, SCAN_NB);
    fill_kernel<<<(NE + 255) / 256, 256, 0, stream>>>(esrc, edst, etyp, start, srcrel, NE);

    // fp16 conversions / packs
    cvt_kernel<<<(NN * 32 + 255) / 256, 256, 0, stream>>>(x, xh, NN * 32);
    pack_b_kernel<<<(1152 * 128 + 255) / 256, 256, 0, stream>>>(W1, root1, Bt1, 128);
    pack_b_kernel<<<(576 * 128 + 255) / 256, 256, 0, stream>>>(W2, root2, Bt2, 64);

    const int agrid = (NN + 3) / 4;            // one wave per dst, 4 waves/block
    const int gy = (NN + 63) / 64;             // 64-row GEMM tiles

    // layer 1: transform xh -> xW [NN,1152], aggregate (+root+bias) -> h1b fp16
    gemm_xw<1152><<<dim3(1152 / 64, gy), 256, 0, stream>>>(xh, Bt1, xW);
    agg_kernel<128, false><<<agrid, 256, 0, stream>>>(rp, srcrel, inv, xW, b1, h1b);

    // layer 2: transform h1b -> xW2 [NN,576], aggregate (+root+bias+sigmoid) -> out fp32
    gemm_xw<576><<<dim3(576 / 64, gy), 256, 0, stream>>>(h1b, Bt2, xW2);
    agg_kernel<64, true><<<agrid, 256, 0, stream>>>(rp, srcrel, inv, xW2, b2, out);
}

// Round 12
// 330.663 us; speedup vs baseline: 1.3687x; 1.3687x over previous
//
#include <hip/hip_runtime.h>
#include <math.h>

#define NN 50000
#define NE 640000
#define NR 8
#define SCAN_N (NN * NR)  // 400000 segments
#define SCAN_CH 2048      // elements per scan block
#define SCAN_NB ((SCAN_N + SCAN_CH - 1) / SCAN_CH)  // 196

// prep_kernel block-range partition
#define PREP_COUNT_NB ((NE + 255) / 256)              // 2500
#define PREP_CVT_NB   ((NN * 32 + 255) / 256)         // 6250
#define PREP_PK1_NB   ((1152 * 128 + 255) / 256)      // 576
#define PREP_PK2_NB   ((576 * 128 + 255) / 256)       // 288
#define PREP_NB (PREP_COUNT_NB + PREP_CVT_NB + PREP_PK1_NB + PREP_PK2_NB)

typedef __attribute__((ext_vector_type(8))) _Float16 half8;
typedef __attribute__((ext_vector_type(8))) short short8;
typedef __attribute__((ext_vector_type(4))) float f32x4;
typedef const void __attribute__((address_space(1))) gvoid_t;
typedef void __attribute__((address_space(3))) svoid_t;

__device__ __forceinline__ unsigned short f2h(float f) {
    _Float16 h = (_Float16)f;                       // v_cvt_f16_f32, RNE
    return __builtin_bit_cast(unsigned short, h);
}
__device__ __forceinline__ float h2f(unsigned short u) {
    return (float)__builtin_bit_cast(_Float16, u);
}

// ---------- fused prep: edge count histogram | x->fp16 | weight packs ----------
__global__ __launch_bounds__(256) void prep_kernel(const int* __restrict__ dst,
                                                   const int* __restrict__ typ,
                                                   int* __restrict__ cnt,
                                                   const float* __restrict__ x,
                                                   unsigned short* __restrict__ xh,
                                                   const float* __restrict__ W1,
                                                   const float* __restrict__ root1,
                                                   unsigned short* __restrict__ Bt1,
                                                   const float* __restrict__ W2,
                                                   const float* __restrict__ root2,
                                                   unsigned short* __restrict__ Bt2) {
    int b = blockIdx.x;
    if (b < PREP_COUNT_NB) {
        int e = b * 256 + threadIdx.x;
        if (e < NE) atomicAdd(&cnt[dst[e] * NR + typ[e]], 1);
        return;
    }
    b -= PREP_COUNT_NB;
    if (b < PREP_CVT_NB) {
        int i = b * 256 + threadIdx.x;   // i < NN*32 always (6250*256 == NN*32)
        float4 v = ((const float4*)x)[i];
        uint2 u;
        u.x = (unsigned)f2h(v.x) | ((unsigned)f2h(v.y) << 16);
        u.y = (unsigned)f2h(v.z) | ((unsigned)f2h(v.w) << 16);
        ((uint2*)xh)[i] = u;
        return;
    }
    b -= PREP_CVT_NB;
    if (b < PREP_PK1_NB) {
        // Bt1[n][k], n in [0,1152): n<1024 -> W1[r=n/128][k][o=n%128], else root1[k][n-1024]
        int i = b * 256 + threadIdx.x;   // i < 1152*128 exactly
        int k = i & 127, n = i >> 7;
        float v = (n < 1024) ? W1[(size_t)(n >> 7) * 128 * 128 + (size_t)k * 128 + (n & 127)]
                             : root1[(size_t)k * 128 + (n - 1024)];
        Bt1[(size_t)n * 128 + k] = f2h(v);
        return;
    }
    b -= PREP_PK1_NB;
    {
        // Bt2[n][k], n in [0,576): n<512 -> W2[r=n/64][k][o=n%64], else root2[k][n-512]
        int i = b * 256 + threadIdx.x;   // i < 576*128 exactly
        int k = i & 127, n = i >> 7;
        float v = (n < 512) ? W2[(size_t)(n >> 6) * 128 * 64 + (size_t)k * 64 + (n & 63)]
                            : root2[(size_t)k * 64 + (n - 512)];
        Bt2[(size_t)n * 128 + k] = f2h(v);
    }
}

// ---- hierarchical scan (inv fused into pass 1)
__global__ __launch_bounds__(256) void scan1_kernel(const int* __restrict__ cnt,
                                                    float* __restrict__ inv,
                                                    int* __restrict__ loc,
                                                    int* __restrict__ bsum) {
    __shared__ int s[256];
    const int t = threadIdx.x;
    const int base = blockIdx.x * SCAN_CH + t * 8;
    int v[8];
    int sum = 0;
#pragma unroll
    for (int j = 0; j < 8; ++j) {
        int idx = base + j;
        v[j] = (idx < SCAN_N) ? cnt[idx] : 0;
        sum += v[j];
    }
#pragma unroll
    for (int j = 0; j < 8; ++j) {
        int idx = base + j;
        if (idx < SCAN_N) inv[idx] = 1.0f / (float)(v[j] > 1 ? v[j] : 1);
    }
    s[t] = sum;
    __syncthreads();
    for (int off = 1; off < 256; off <<= 1) {
        int u = (t >= off) ? s[t - off] : 0;
        __syncthreads();
        s[t] += u;
        __syncthreads();
    }
    int run = (t == 0) ? 0 : s[t - 1];
#pragma unroll
    for (int j = 0; j < 8; ++j) {
        int idx = base + j;
        if (idx < SCAN_N) loc[idx] = run;
        run += v[j];
    }
    if (t == 255) bsum[blockIdx.x] = s[255];
}

__global__ __launch_bounds__(256) void scan2_kernel(const int* __restrict__ bsum,
                                                    int* __restrict__ boff, int nb) {
    __shared__ int s[256];
    const int t = threadIdx.x;
    s[t] = (t < nb) ? bsum[t] : 0;
    __syncthreads();
    for (int off = 1; off < 256; off <<= 1) {
        int u = (t >= off) ? s[t - off] : 0;
        __syncthreads();
        s[t] += u;
        __syncthreads();
    }
    if (t < nb) boff[t] = (t == 0) ? 0 : s[t - 1];
    if (t == nb - 1) boff[nb] = s[t];
}

__global__ __launch_bounds__(256) void scan3_kernel(int* __restrict__ rowptr,
                                                    int* __restrict__ start,
                                                    const int* __restrict__ boff, int nb) {
    const int b = blockIdx.x, t = threadIdx.x;
    const int add = boff[b];
#pragma unroll
    for (int j = 0; j < 8; ++j) {
        int idx = b * SCAN_CH + t * 8 + j;
        if (idx < SCAN_N) {
            int v = rowptr[idx] + add;
            rowptr[idx] = v;
            start[idx] = v;
        }
    }
    if (b == 0 && t == 0) rowptr[SCAN_N] = boff[nb];
}

// counting-sort by (dst,rel): srcrel[pos] = src | rel<<20
__global__ __launch_bounds__(256) void fill_kernel(const int* __restrict__ src,
                                                   const int* __restrict__ dst,
                                                   const int* __restrict__ typ,
                                                   int* __restrict__ start,
                                                   int* __restrict__ srcrel, int E) {
    int e = blockIdx.x * 256 + threadIdx.x;
    if (e >= E) return;
    int r = typ[e];
    int pos = atomicAdd(&start[dst[e] * NR + r], 1);
    srcrel[pos] = src[e] | (r << 20);
}

// ---------- fp16 MFMA GEMM: C[M,LDC] = A[M,128] @ Bt[LDC,128]^T, fp16 out ----------
// R7 staging (2-phase BK=64, 16KB LDS, no swizzle — conflicts proven non-binding)
// + R8 proven-correct swapped-operand epilogue with plain contiguous 8B stores.
template <int LDC>
__global__ __launch_bounds__(256) void gemm_xw(const unsigned short* __restrict__ A,
                                               const unsigned short* __restrict__ Bt,
                                               unsigned short* __restrict__ C) {
    __shared__ __align__(16) unsigned short As[64 * 64];
    __shared__ __align__(16) unsigned short Bs[64 * 64];
    const int t = threadIdx.x;
    const int w = t >> 6, lane = t & 63;
    const int q = lane >> 4, m = lane & 15;
    const int wr = w >> 1, wc = w & 1;     // 2x2 wave grid: 32x32 per wave
    const int bm = blockIdx.y * 64;
    const int bn = blockIdx.x * 64;

    f32x4 acc[2][2];
#pragma unroll
    for (int mb = 0; mb < 2; ++mb)
#pragma unroll
        for (int nb = 0; nb < 2; ++nb) acc[mb][nb] = (f32x4)0.f;

    const int srow = lane >> 3, schk = lane & 7;   // lane -> (row-in-8, 16B chunk)

#pragma unroll
    for (int kc = 0; kc < 2; ++kc) {
        const int k0 = kc * 64;
        // A tile: 64 rows x 64 fp16 (8 KB)
#pragma unroll
        for (int ii = 0; ii < 2; ++ii) {
            int i = w * 2 + ii;
            int grow = bm + i * 8 + srow;
            if (grow >= NN) grow = NN - 1;
            const unsigned short* g = A + (size_t)grow * 128 + k0 + schk * 8;
            __builtin_amdgcn_global_load_lds((gvoid_t*)g, (svoid_t*)(As + i * 512), 16, 0, 0);
        }
        // B tile: 64 rows of Bt x 64 fp16
#pragma unroll
        for (int ii = 0; ii < 2; ++ii) {
            int i = w * 2 + ii;
            const unsigned short* g = Bt + (size_t)(bn + i * 8 + srow) * 128 + k0 + schk * 8;
            __builtin_amdgcn_global_load_lds((gvoid_t*)g, (svoid_t*)(Bs + i * 512), 16, 0, 0);
        }
        __syncthreads();
#pragma unroll
        for (int s = 0; s < 2; ++s) {
            half8 af[2], bf[2];
#pragma unroll
            for (int mb = 0; mb < 2; ++mb)
                af[mb] = __builtin_bit_cast(half8,
                    *(const short8*)(As + (wr * 32 + mb * 16 + m) * 64 + s * 32 + q * 8));
#pragma unroll
            for (int nb = 0; nb < 2; ++nb)
                bf[nb] = __builtin_bit_cast(half8,
                    *(const short8*)(Bs + (wc * 32 + nb * 16 + m) * 64 + s * 32 + q * 8));
#pragma unroll
            for (int mb = 0; mb < 2; ++mb)
#pragma unroll
                for (int nb = 0; nb < 2; ++nb)
                    acc[mb][nb] = __builtin_amdgcn_mfma_f32_16x16x32_f16(bf[nb], af[mb],
                                                                         acc[mb][nb], 0, 0, 0);
        }
        __syncthreads();
    }

    // epilogue (swapped-operand layout): row = block + m, cols = q*4 + j (contiguous)
#pragma unroll
    for (int mb = 0; mb < 2; ++mb) {
        int grow = bm + wr * 32 + mb * 16 + m;
        if (grow >= NN) continue;
#pragma unroll
        for (int nb = 0; nb < 2; ++nb) {
            int col = bn + wc * 32 + nb * 16 + q * 4;
            ushort4 u;
            u.x = f2h(acc[mb][nb][0]);
            u.y = f2h(acc[mb][nb][1]);
            u.z = f2h(acc[mb][nb][2]);
            u.w = f2h(acc[mb][nb][3]);
            *(ushort4*)(C + (size_t)grow * LDC + col) = u;
        }
    }
}

// ---------- aggregation over transformed messages: one wave per dst ----------
// O=128: h[dst] = sum_e half2(XW[src_e, r_e*128 + 2*lane..]) * inv[dst,r_e]
//                 + XW[dst, 1024..] + bias  -> fp16 h1b
// O=64, FINAL: scalar per lane + sigmoid -> fp32 out
template <int O, bool FINAL>
__global__ __launch_bounds__(256) void agg_kernel(const int* __restrict__ rp,
                                                  const int* __restrict__ srcrel,
                                                  const float* __restrict__ inv,
                                                  const unsigned short* __restrict__ XW,
                                                  const float* __restrict__ bias,
                                                  void* __restrict__ Hout) {
    __shared__ float sinv[4][8];
    const int slot = threadIdx.x >> 6, lane = threadIdx.x & 63;
    const int w = blockIdx.x * 4 + slot;
    if (w >= NN) return;
    if (lane < 8) sinv[slot][lane] = inv[w * NR + lane];   // wave-synchronous, no barrier

    const int beg = rp[w * NR], end = rp[w * NR + NR];
    constexpr int LDC2 = 9 * O / 2;          // row stride in half2 units (576 or 288)

    if (O == 128) {
        const unsigned int* X2 = (const unsigned int*)XW;   // half2 units
        float2 acc = make_float2(0.f, 0.f);
        int i = beg;
        for (; i + 3 < end; i += 4) {        // 4 gathers in flight
            int p0 = srcrel[i], p1 = srcrel[i + 1], p2 = srcrel[i + 2], p3 = srcrel[i + 3];
            unsigned g0 = X2[(size_t)(p0 & 0xFFFFF) * LDC2 + (((unsigned)p0) >> 20) * 64 + lane];
            unsigned g1 = X2[(size_t)(p1 & 0xFFFFF) * LDC2 + (((unsigned)p1) >> 20) * 64 + lane];
            unsigned g2 = X2[(size_t)(p2 & 0xFFFFF) * LDC2 + (((unsigned)p2) >> 20) * 64 + lane];
            unsigned g3 = X2[(size_t)(p3 & 0xFFFFF) * LDC2 + (((unsigned)p3) >> 20) * 64 + lane];
            float s0 = sinv[slot][((unsigned)p0) >> 20];
            float s1 = sinv[slot][((unsigned)p1) >> 20];
            float s2 = sinv[slot][((unsigned)p2) >> 20];
            float s3 = sinv[slot][((unsigned)p3) >> 20];
            acc.x += h2f((unsigned short)(g0 & 0xFFFFu)) * s0;
            acc.y += h2f((unsigned short)(g0 >> 16)) * s0;
            acc.x += h2f((unsigned short)(g1 & 0xFFFFu)) * s1;
            acc.y += h2f((unsigned short)(g1 >> 16)) * s1;
            acc.x += h2f((unsigned short)(g2 & 0xFFFFu)) * s2;
            acc.y += h2f((unsigned short)(g2 >> 16)) * s2;
            acc.x += h2f((unsigned short)(g3 & 0xFFFFu)) * s3;
            acc.y += h2f((unsigned short)(g3 >> 16)) * s3;
        }
        for (; i < end; ++i) {
            int p0 = srcrel[i];
            unsigned g0 = X2[(size_t)(p0 & 0xFFFFF) * LDC2 + (((unsigned)p0) >> 20) * 64 + lane];
            float s0 = sinv[slot][((unsigned)p0) >> 20];
            acc.x += h2f((unsigned short)(g0 & 0xFFFFu)) * s0;
            acc.y += h2f((unsigned short)(g0 >> 16)) * s0;
        }
        // root block (cols 1024..1151 = half2 512..575) + bias
        unsigned rt = X2[(size_t)w * LDC2 + 512 + lane];
        float2 bv = ((const float2*)bias)[lane];
        float vx = acc.x + h2f((unsigned short)(rt & 0xFFFFu)) + bv.x;
        float vy = acc.y + h2f((unsigned short)(rt >> 16)) + bv.y;
        ((unsigned int*)Hout)[(size_t)w * 64 + lane] =
            (unsigned)f2h(vx) | ((unsigned)f2h(vy) << 16);
    } else {
        constexpr int LDC = 9 * O;           // 576
        float acc = 0.f;
        int i = beg;
        for (; i + 3 < end; i += 4) {
            int p0 = srcrel[i], p1 = srcrel[i + 1], p2 = srcrel[i + 2], p3 = srcrel[i + 3];
            unsigned short g0 = XW[(size_t)(p0 & 0xFFFFF) * LDC + (((unsigned)p0) >> 20) * 64 + lane];
            unsigned short g1 = XW[(size_t)(p1 & 0xFFFFF) * LDC + (((unsigned)p1) >> 20) * 64 + lane];
            unsigned short g2 = XW[(size_t)(p2 & 0xFFFFF) * LDC + (((unsigned)p2) >> 20) * 64 + lane];
            unsigned short g3 = XW[(size_t)(p3 & 0xFFFFF) * LDC + (((unsigned)p3) >> 20) * 64 + lane];
            acc += h2f(g0) * sinv[slot][((unsigned)p0) >> 20];
            acc += h2f(g1) * sinv[slot][((unsigned)p1) >> 20];
            acc += h2f(g2) * sinv[slot][((unsigned)p2) >> 20];
            acc += h2f(g3) * sinv[slot][((unsigned)p3) >> 20];
        }
        for (; i < end; ++i) {
            int p0 = srcrel[i];
            unsigned short g0 = XW[(size_t)(p0 & 0xFFFFF) * LDC + (((unsigned)p0) >> 20) * 64 + lane];
            acc += h2f(g0) * sinv[slot][((unsigned)p0) >> 20];
        }
        float v = acc + h2f(XW[(size_t)w * LDC + 512 + lane]) + bias[lane];
        ((float*)Hout)[(size_t)w * 64 + lane] = 1.f / (1.f + __expf(-v));
    }
}

extern "C" void kernel_launch(void* const* d_in, const int* in_sizes, int n_in,
                              void* d_out, int out_size, void* d_ws, size_t ws_size,
                              hipStream_t stream) {
    const float* x     = (const float*)d_in[0];
    const int*   esrc  = (const int*)d_in[1];
    const int*   edst  = (const int*)d_in[2];
    const int*   etyp  = (const int*)d_in[3];
    const float* W1    = (const float*)d_in[4];
    const float* root1 = (const float*)d_in[5];
    const float* b1    = (const float*)d_in[6];
    const float* W2    = (const float*)d_in[7];
    const float* root2 = (const float*)d_in[8];
    const float* b2    = (const float*)d_in[9];
    float* out = (float*)d_out;

    char* ws = (char*)d_ws;
    unsigned short* Bt1    = (unsigned short*)ws; ws += (size_t)1152 * 128 * 2; // 288 KB
    unsigned short* Bt2    = (unsigned short*)ws; ws += (size_t)576 * 128 * 2;  // 144 KB
    int*            cnt    = (int*)ws;            ws += (size_t)SCAN_N * 4;     // 1.6 MB
    float*          inv    = (float*)ws;          ws += (size_t)SCAN_N * 4;     // 1.6 MB
    int*            rp     = (int*)ws;            ws += (size_t)(SCAN_N + 64) * 4;
    int*            start  = (int*)ws;            ws += (size_t)SCAN_N * 4;     // 1.6 MB
    int*            bsum   = (int*)ws;            ws += (size_t)256 * 4;
    int*            boff   = (int*)ws;            ws += (size_t)257 * 4;
    int*            srcrel = (int*)ws;            ws += (size_t)NE * 4;         // 2.56 MB
    unsigned short* xh     = (unsigned short*)ws; ws += (size_t)NN * 128 * 2;   // 12.8 MB
    unsigned short* h1b    = (unsigned short*)ws; ws += (size_t)NN * 128 * 2;   // 12.8 MB
    unsigned short* xW     = (unsigned short*)ws;                               // 115.2 MB
    unsigned short* xW2    = xW;   // layer-2 transform aliases (xW dead after agg1)

    // fused prep (count histogram | x->fp16 | weight packs) after zeroing cnt
    (void)hipMemsetAsync(cnt, 0, (size_t)SCAN_N * 4, stream);
    prep_kernel<<<PREP_NB, 256, 0, stream>>>(edst, etyp, cnt, x, xh,
                                             W1, root1, Bt1, W2, root2, Bt2);

    // CSR by (dst, rel) — hierarchical scan (inv fused into pass 1)
    scan1_kernel<<<SCAN_NB, 256, 0, stream>>>(cnt, inv, rp, bsum);
    scan2_kernel<<<1, 256, 0, stream>>>(bsum, boff, SCAN_NB);
    scan3_kernel<<<SCAN_NB, 256, 0, stream>>>(rp, start, boff, SCAN_NB);
    fill_kernel<<<(NE + 255) / 256, 256, 0, stream>>>(esrc, edst, etyp, start, srcrel, NE);

    const int agrid = (NN + 3) / 4;            // one wave per dst, 4 waves/block
    const int gy = (NN + 63) / 64;             // 64-row GEMM tiles

    // layer 1: transform xh -> xW [NN,1152], aggregate (+root+bias) -> h1b fp16
    gemm_xw<1152><<<dim3(1152 / 64, gy), 256, 0, stream>>>(xh, Bt1, xW);
    agg_kernel<128, false><<<agrid, 256, 0, stream>>>(rp, srcrel, inv, xW, b1, h1b);

    // layer 2: transform h1b -> xW2 [NN,576], aggregate (+root+bias+sigmoid) -> out fp32
    gemm_xw<576><<<dim3(576 / 64, gy), 256, 0, stream>>>(h1b, Bt2, xW2);
    agg_kernel<64, true><<<agrid, 256, 0, stream>>>(rp, srcrel, inv, xW2, b2, out);
}